// Round 1
// 224.180 us; speedup vs baseline: 1.0038x; 1.0038x over previous
//
#include <hip/hip_runtime.h>
#include <hip/hip_bf16.h>

// B=2, T=2048, E=1024, H=16, D=64. Inputs f32 (+ int32 mask), output f32.
// Internal bf16 MFMA pipeline.
// prep: ONE dispatch = embed f32->bf16 convert + 4x weight transpose+cast
//       + mask int32 -> 1-bit bitmask (1MB, L2-resident).
// GEMMs: round-7 ASYNC16 2-barrier structure verbatim (known good).
// Flash: round-7 structure + bitmask; THIS ROUND:
//   (a) row-sum l_i via MFMA with a ones-fragment (reuses pf, runs on the
//       82%-idle matrix pipe; removes 16 cvt + 16 add + 2 shfl from the
//       VALU-bound softmax chain)
//   (b) s_setprio(1) around the MFMA clusters (T5, attn-proven +4-7%)

typedef __bf16 bf8_t  __attribute__((ext_vector_type(8)));
typedef __bf16 bf4_t  __attribute__((ext_vector_type(4)));
typedef float  f4_t   __attribute__((ext_vector_type(4)));

constexpr int Bb = 2, Tt = 2048, Hh = 16, Dd = 64;

#define ASYNC16(g, l)                                                        \
    __builtin_amdgcn_global_load_lds(                                        \
        (const __attribute__((address_space(1))) void*)(g),                  \
        (__attribute__((address_space(3))) void*)(l), 16, 0, 0)

#if __has_builtin(__builtin_amdgcn_exp2f)
#define EXP2F(x) __builtin_amdgcn_exp2f(x)
#else
#define EXP2F(x) exp2f(x)
#endif

// ---------------------------------------------------------------- prep
// blockIdx.x decode: [0,4096) transpose W (z>>10 = which matrix),
// [4096,5120) convert embed, [5120,6144) build bitmask.
__global__ __launch_bounds__(256) void prep_kernel(
    const float* __restrict__ embed, const int* __restrict__ mask,
    const float* __restrict__ w0, const float* __restrict__ w1,
    const float* __restrict__ w2, const float* __restrict__ w3,
    __bf16* __restrict__ o0, __bf16* __restrict__ o1,
    __bf16* __restrict__ o2, __bf16* __restrict__ o3,
    __bf16* __restrict__ Eb, unsigned* __restrict__ Mbits)
{
    int z = blockIdx.x;
    if (z < 4096) {
        const float* in; __bf16* out;
        switch (z >> 10) {
            case 0: in = w0; out = o0; break;
            case 1: in = w1; out = o1; break;
            case 2: in = w2; out = o2; break;
            default: in = w3; out = o3; break;
        }
        int rem = z & 1023;
        int bx = (rem & 31) * 32;      // n offset
        int by = (rem >> 5) * 32;      // k offset
        __shared__ float t[32][33];
        int x  = threadIdx.x & 31;
        int y0 = threadIdx.x >> 5;
        #pragma unroll
        for (int i = 0; i < 4; i++) {
            int y = y0 + i * 8;
            t[y][x] = in[(size_t)(by + y) * 1024 + bx + x];
        }
        __syncthreads();
        #pragma unroll
        for (int i = 0; i < 4; i++) {
            int y = y0 + i * 8;
            out[(size_t)(bx + y) * 1024 + by + x] = (__bf16)t[x][y];
        }
    } else if (z < 5120) {
        size_t base = (size_t)(z - 4096) * 4096;
        #pragma unroll
        for (int j = 0; j < 4; j++) {
            size_t i = base + j * 1024 + threadIdx.x * 4;
            float4 v = *reinterpret_cast<const float4*>(embed + i);
            bf4_t o = {(__bf16)v.x, (__bf16)v.y, (__bf16)v.z, (__bf16)v.w};
            *reinterpret_cast<bf4_t*>(Eb + i) = o;
        }
    } else {
        // word g covers mask[g*32 .. g*32+32)
        size_t g = (size_t)(z - 5120) * 256 + threadIdx.x;
        const int* mp = mask + g * 32;
        unsigned v = 0;
        #pragma unroll
        for (int i = 0; i < 8; i++) {
            int4 m4 = *reinterpret_cast<const int4*>(mp + i * 4);
            if (m4.x) v |= 1u << (i * 4 + 0);
            if (m4.y) v |= 1u << (i * 4 + 1);
            if (m4.z) v |= 1u << (i * 4 + 2);
            if (m4.w) v |= 1u << (i * 4 + 3);
        }
        Mbits[g] = v;
    }
}

// ---------------------------------------------------------------- GEMM body
// round-7 structure verbatim: ASYNC16 staging, 2 barriers/iter, XOR swizzle.
template <int TM, typename OutT>
__device__ __forceinline__ void gemm_body(const __bf16* __restrict__ A,
                                          const __bf16* __restrict__ Bt,
                                          const float* __restrict__ bias,
                                          OutT* __restrict__ out,
                                          int mode, float oscale, int bx, int by)
{
    constexpr int NI = TM / 32;
    alignas(16) __shared__ __bf16 As[TM * 64];
    alignas(16) __shared__ __bf16 Bs[128 * 64];

    int tid  = threadIdx.x;
    int lane = tid & 63;
    int quad = lane >> 4;
    int l16  = lane & 15;
    int wave = tid >> 6;
    int wm   = wave >> 1, wn = wave & 1;

    f4_t acc[NI][4];
    #pragma unroll
    for (int i = 0; i < NI; i++)
        #pragma unroll
        for (int j = 0; j < 4; j++)
            acc[i][j] = f4_t{0.f, 0.f, 0.f, 0.f};

    for (int kt = 0; kt < 1024; kt += 64) {
        #pragma unroll
        for (int i = 0; i < TM / 32; i++) {
            int c   = tid + 256 * i;
            int row = c >> 3, j = c & 7;
            ASYNC16(A + (size_t)(by * TM + row) * 1024 + kt + ((j ^ (row & 7)) * 8),
                    &As[c * 8]);
        }
        #pragma unroll
        for (int i = 0; i < 4; i++) {
            int c   = tid + 256 * i;
            int row = c >> 3, j = c & 7;
            ASYNC16(Bt + (size_t)(bx * 128 + row) * 1024 + kt + ((j ^ (row & 7)) * 8),
                    &Bs[c * 8]);
        }
        __syncthreads();

        bf8_t af[2][NI], bfr[2][4];
        #pragma unroll
        for (int c = 0; c < 2; c++) {
            #pragma unroll
            for (int im = 0; im < NI; im++) {
                int row = wm * (TM / 2) + im * 16 + l16;
                af[c][im] = *reinterpret_cast<const bf8_t*>(
                    &As[row * 64 + (((c * 4 + quad) ^ (row & 7)) * 8)]);
            }
            #pragma unroll
            for (int in_ = 0; in_ < 4; in_++) {
                int row = wn * 64 + in_ * 16 + l16;
                bfr[c][in_] = *reinterpret_cast<const bf8_t*>(
                    &Bs[row * 64 + (((c * 4 + quad) ^ (row & 7)) * 8)]);
            }
        }
        #pragma unroll
        for (int c = 0; c < 2; c++)
            #pragma unroll
            for (int im = 0; im < NI; im++)
                #pragma unroll
                for (int in_ = 0; in_ < 4; in_++)
                    acc[im][in_] = __builtin_amdgcn_mfma_f32_16x16x32_bf16(
                        af[c][im], bfr[c][in_], acc[im][in_], 0, 0, 0);
        __syncthreads();
    }

    #pragma unroll
    for (int im = 0; im < NI; im++) {
        #pragma unroll
        for (int in_ = 0; in_ < 4; in_++) {
            int gc  = bx * 128 + wn * 64 + in_ * 16 + l16;
            float bb = bias[gc];
            int gr0 = by * TM + wm * (TM / 2) + im * 16 + quad * 4;
            if (mode == 2) {
                int b = gr0 >> 11, t0 = gr0 & 2047;
                int h = gc >> 6,  d = gc & 63;
                bf4_t ov;
                #pragma unroll
                for (int r = 0; r < 4; r++)
                    ov[r] = (__bf16)(acc[im][in_][r] + bb);
                *reinterpret_cast<bf4_t*>(
                    (__bf16*)out + ((size_t)(b * Hh + h) * Dd + d) * Tt + t0) = ov;
            } else {
                #pragma unroll
                for (int r = 0; r < 4; r++) {
                    int gr  = gr0 + r;
                    float v = (acc[im][in_][r] + bb) * oscale;
                    size_t idx;
                    if (mode == 0) {
                        idx = (size_t)gr * 1024 + gc;
                    } else {
                        int b = gr >> 11, t = gr & 2047;
                        int h = gc >> 6,  d = gc & 63;
                        idx = ((size_t)(b * Hh + h) * Tt + t) * Dd + d;
                    }
                    out[idx] = (OutT)v;
                }
            }
        }
    }
}

__global__ __launch_bounds__(256) void gemm_qkv_kernel(
    const __bf16* __restrict__ A,
    const __bf16* __restrict__ WqT, const __bf16* __restrict__ WkT, const __bf16* __restrict__ WvT,
    const float* __restrict__ bq,  const float* __restrict__ bk,  const float* __restrict__ bv,
    __bf16* __restrict__ Qo, __bf16* __restrict__ Ko, __bf16* __restrict__ Vo)
{
    const __bf16* Bt; const float* bias; __bf16* out; int mode; float sc;
    // Q carries 0.125 * log2(e) so flash softmax runs in exp2 domain.
    if      (blockIdx.z == 0) { Bt = WqT; bias = bq; out = Qo; mode = 1; sc = 0.18033688011112042f; }
    else if (blockIdx.z == 1) { Bt = WkT; bias = bk; out = Ko; mode = 1; sc = 1.f; }
    else                      { Bt = WvT; bias = bv; out = Vo; mode = 2; sc = 1.f; }
    gemm_body<128, __bf16>(A, Bt, bias, out, mode, sc, blockIdx.x, blockIdx.y);
}

__global__ __launch_bounds__(256) void gemm_out_kernel(
    const __bf16* __restrict__ A, const __bf16* __restrict__ Bt,
    const float* __restrict__ bias, float* __restrict__ out)
{
    gemm_body<64, float>(A, Bt, bias, out, 0, 1.f, blockIdx.x, blockIdx.y);
}

// ---------------------------------------------------------------- flash attn
// Round-7 structure; mask via bitmask u64 (bits [kt,kt+64) of query row).
// grid (T/128, H, B), 512 threads = 8 waves. Dbuf LDS, one barrier/iter,
// reg-staged K/V prefetch issued after the barrier.
// l_i computed by MFMA against a ones-fragment (matrix pipe is ~82% idle);
// softmax VALU chain keeps only mask-select + exp2 + bf16 pack.
__global__ __launch_bounds__(512, 4) void flash_kernel(
    const __bf16* __restrict__ Qb, const __bf16* __restrict__ Kb,
    const __bf16* __restrict__ Vb, const unsigned* __restrict__ Mbits,
    __bf16* __restrict__ Zb)
{
    alignas(16) __shared__ __bf16 Ks[2][64 * 64];   // swizzled, 8KB each
    alignas(16) __shared__ __bf16 Vs[2][64 * 64];
    alignas(16) __shared__ __bf16 Ps[8 * 16 * 72];  // per-wave P^T, 18KB

    int tid  = threadIdx.x;
    int lane = tid & 63;
    int wave = tid >> 6;
    int quad = lane >> 4;
    int l16  = lane & 15;
    int b = blockIdx.z, h = blockIdx.y;
    int bh = b * Hh + h;
    int qrow = blockIdx.x * 128 + wave * 16;

    int srow = tid >> 3, sj = tid & 7;
    const __bf16* kgp = Kb + ((size_t)bh * Tt + srow) * Dd + ((sj ^ (srow & 7)) * 8);
    const __bf16* vgp = Vb + ((size_t)bh * Dd + srow) * Tt + ((sj ^ (srow & 7)) * 8);
    const int sdst = tid * 8;

    bf8_t qf[2];
    #pragma unroll
    for (int c = 0; c < 2; c++)
        qf[c] = *reinterpret_cast<const bf8_t*>(
            Qb + ((size_t)bh * Tt + qrow + l16) * Dd + c * 32 + quad * 8);

    // ones-fragment for the l_i row-sum MFMA (A = all-ones 16x32 tile)
    bf8_t ones;
    #pragma unroll
    for (int i = 0; i < 8; i++) ones[i] = (__bf16)1.0f;

    // bitmask row for this lane's query: 64 words/row, u64 per 64-key tile
    const unsigned* bmp = Mbits + ((size_t)b * Tt + qrow + l16) * 64;

    f4_t lacc = f4_t{0.f, 0.f, 0.f, 0.f};
    f4_t o[4];
    #pragma unroll
    for (int d = 0; d < 4; d++) o[d] = f4_t{0.f, 0.f, 0.f, 0.f};

    __bf16* pw = Ps + wave * 16 * 72;

    // prime: tile 0 into regs
    bf8_t kreg = *reinterpret_cast<const bf8_t*>(kgp);
    bf8_t vreg = *reinterpret_cast<const bf8_t*>(vgp);
    unsigned long long mreg = *reinterpret_cast<const unsigned long long*>(bmp);

    for (int kt = 0; kt < Tt; kt += 64) {
        int par = (kt >> 6) & 1;
        *reinterpret_cast<bf8_t*>(&Ks[par][sdst]) = kreg;
        *reinterpret_cast<bf8_t*>(&Vs[par][sdst]) = vreg;
        // per-n 4-bit nibbles for this lane's quad, captured before reload
        unsigned nib[4];
        #pragma unroll
        for (int n = 0; n < 4; n++)
            nib[n] = (unsigned)(mreg >> (n * 16 + quad * 4)) & 0xFu;
        __syncthreads();

        // prefetch next tile (issued after barrier -> not drained by it)
        int ktn = (kt + 64 < Tt) ? kt + 64 : 0;
        kreg = *reinterpret_cast<const bf8_t*>(kgp + (size_t)ktn * Dd);
        vreg = *reinterpret_cast<const bf8_t*>(vgp + ktn);
        mreg = *reinterpret_cast<const unsigned long long*>(bmp + (ktn >> 5));

        // S^T = K Q^T : 4 key-subtiles x 2 d-chunks
        f4_t s[4];
        #pragma unroll
        for (int n = 0; n < 4; n++) s[n] = f4_t{0.f, 0.f, 0.f, 0.f};
        __builtin_amdgcn_s_setprio(1);
        #pragma unroll
        for (int c = 0; c < 2; c++)
            #pragma unroll
            for (int n = 0; n < 4; n++) {
                int krow = n * 16 + l16;
                bf8_t kf = *reinterpret_cast<const bf8_t*>(
                    &Ks[par][krow * 64 + (((c * 4 + quad) ^ (krow & 7)) * 8)]);
                s[n] = __builtin_amdgcn_mfma_f32_16x16x32_bf16(kf, qf[c], s[n], 0, 0, 0);
            }
        __builtin_amdgcn_s_setprio(0);

        // p = mask-bit ? exp2(s) : 0; P^T -> LDS (row-sum now via MFMA below)
        #pragma unroll
        for (int n = 0; n < 4; n++) {
            bf4_t pv4;
            #pragma unroll
            for (int r = 0; r < 4; r++) {
                float p = (nib[n] & (1u << r)) ? EXP2F(s[n][r]) : 0.f;
                pv4[r] = (__bf16)p;
            }
            *reinterpret_cast<bf4_t*>(&pw[l16 * 72 + n * 16 + quad * 4]) = pv4;
        }

        // O^T += V^T @ P^T over 64 keys (2 chunks); l_i += ones @ P^T
        __builtin_amdgcn_s_setprio(1);
        #pragma unroll
        for (int c = 0; c < 2; c++) {
            bf8_t pf = *reinterpret_cast<const bf8_t*>(
                &pw[l16 * 72 + c * 32 + quad * 8]);
            lacc = __builtin_amdgcn_mfma_f32_16x16x32_bf16(ones, pf, lacc, 0, 0, 0);
            #pragma unroll
            for (int ds = 0; ds < 4; ds++) {
                int vrow = ds * 16 + l16;
                bf8_t vf = *reinterpret_cast<const bf8_t*>(
                    &Vs[par][vrow * 64 + (((c * 4 + quad) ^ (vrow & 7)) * 8)]);
                o[ds] = __builtin_amdgcn_mfma_f32_16x16x32_bf16(vf, pf, o[ds], 0, 0, 0);
            }
        }
        __builtin_amdgcn_s_setprio(0);
        // no trailing barrier: next iter writes the other buffer.
    }

    // lacc rows are all identical (ones-fragment): lacc[0] = sum_k P[k][q=l16]
    float inv = 1.f / fmaxf(lacc[0], 1e-30f);
    size_t zrow = ((size_t)b * Tt + qrow + l16) * 1024 + h * 64;
    #pragma unroll
    for (int ds = 0; ds < 4; ds++) {
        bf4_t ov;
        #pragma unroll
        for (int r = 0; r < 4; r++) ov[r] = (__bf16)(o[ds][r] * inv);
        *reinterpret_cast<bf4_t*>(Zb + zrow + ds * 16 + quad * 4) = ov;
    }
}

// ---------------------------------------------------------------- launch
extern "C" void kernel_launch(void* const* d_in, const int* in_sizes, int n_in,
                              void* d_out, int out_size, void* d_ws, size_t ws_size,
                              hipStream_t stream)
{
    (void)in_sizes; (void)n_in; (void)out_size; (void)ws_size;

    const float* embed = (const float*)d_in[0];
    const int*   mask  = (const int*)d_in[1];
    const float* Wq = (const float*)d_in[2];
    const float* bq = (const float*)d_in[3];
    const float* Wk = (const float*)d_in[4];
    const float* bk = (const float*)d_in[5];
    const float* Wv = (const float*)d_in[6];
    const float* bv = (const float*)d_in[7];
    const float* Wz = (const float*)d_in[8];
    const float* bz = (const float*)d_in[9];
    float* out = (float*)d_out;

    char* ws = (char*)d_ws;
    const size_t MB = (size_t)1024 * 1024;
    __bf16*   WqT = (__bf16*)(ws + 0 * MB);
    __bf16*   WkT = (__bf16*)(ws + 2 * MB);
    __bf16*   WvT = (__bf16*)(ws + 4 * MB);
    __bf16*   WzT = (__bf16*)(ws + 6 * MB);
    __bf16*   Eb  = (__bf16*)(ws + 8 * MB);
    __bf16*   Qb  = (__bf16*)(ws + 16 * MB);
    __bf16*   Kb  = (__bf16*)(ws + 24 * MB);
    __bf16*   Vb  = (__bf16*)(ws + 32 * MB);
    __bf16*   Zb  = (__bf16*)(ws + 40 * MB);
    unsigned* Mb  = (unsigned*)(ws + 48 * MB);   // bitmask, 1MB -> total 49MB

    prep_kernel<<<dim3(6144), 256, 0, stream>>>(embed, mask, Wq, Wk, Wv, Wz,
                                                WqT, WkT, WvT, WzT, Eb, Mb);
    gemm_qkv_kernel<<<dim3(8, 32, 3), 256, 0, stream>>>(Eb, WqT, WkT, WvT,
                                                        bq, bk, bv, Qb, Kb, Vb);
    flash_kernel<<<dim3(16, Hh, Bb), 512, 0, stream>>>(Qb, Kb, Vb, Mb, Zb);
    gemm_out_kernel<<<dim3(8, 64, 1), 256, 0, stream>>>(Zb, WzT, bz, out);
}